// Round 1
// 56.690 us; speedup vs baseline: 1.0228x; 1.0228x over previous
//
#include <hip/hip_runtime.h>

#define B 2
#define N 256
#define E 256
#define H 768
#define H4 (H / 4)

// ---------------------------------------------------------------------------
// Projection GEMM, split-K: 2 block types, 384 blocks.
//   type 0 (192 blocks): q = x@Wq + bq                      (1 work-unit)
//   type 1 (192 blocks): dual accumulators -> v = x@Wv+bv AND
//                        kvT = (x@Wk + x@Wv + bk + bv)^T    (2 work-units)
// Merging type1+old-type2 removes the duplicate Wv stream: W L2 traffic
// 192 MB -> 144 MB (the floor for 8-row tiles). Block 0 also prescales
// wb[h] = 0.495*we[h] for the energy kernel.
// ---------------------------------------------------------------------------
#define PROJ_STEP(ee, wv, A)                                                  \
    { const float4 xA = *(const float4*)&xs[ee][0];                           \
      const float4 xB = *(const float4*)&xs[ee][4];                           \
      A[0].x = fmaf(xA.x, wv.x, A[0].x); A[0].y = fmaf(xA.x, wv.y, A[0].y);   \
      A[0].z = fmaf(xA.x, wv.z, A[0].z); A[0].w = fmaf(xA.x, wv.w, A[0].w);   \
      A[1].x = fmaf(xA.y, wv.x, A[1].x); A[1].y = fmaf(xA.y, wv.y, A[1].y);   \
      A[1].z = fmaf(xA.y, wv.z, A[1].z); A[1].w = fmaf(xA.y, wv.w, A[1].w);   \
      A[2].x = fmaf(xA.z, wv.x, A[2].x); A[2].y = fmaf(xA.z, wv.y, A[2].y);   \
      A[2].z = fmaf(xA.z, wv.z, A[2].z); A[2].w = fmaf(xA.z, wv.w, A[2].w);   \
      A[3].x = fmaf(xA.w, wv.x, A[3].x); A[3].y = fmaf(xA.w, wv.y, A[3].y);   \
      A[3].z = fmaf(xA.w, wv.z, A[3].z); A[3].w = fmaf(xA.w, wv.w, A[3].w);   \
      A[4].x = fmaf(xB.x, wv.x, A[4].x); A[4].y = fmaf(xB.x, wv.y, A[4].y);   \
      A[4].z = fmaf(xB.x, wv.z, A[4].z); A[4].w = fmaf(xB.x, wv.w, A[4].w);   \
      A[5].x = fmaf(xB.y, wv.x, A[5].x); A[5].y = fmaf(xB.y, wv.y, A[5].y);   \
      A[5].z = fmaf(xB.y, wv.z, A[5].z); A[5].w = fmaf(xB.y, wv.w, A[5].w);   \
      A[6].x = fmaf(xB.z, wv.x, A[6].x); A[6].y = fmaf(xB.z, wv.y, A[6].y);   \
      A[6].z = fmaf(xB.z, wv.z, A[6].z); A[6].w = fmaf(xB.z, wv.w, A[6].w);   \
      A[7].x = fmaf(xB.w, wv.x, A[7].x); A[7].y = fmaf(xB.w, wv.y, A[7].y);   \
      A[7].z = fmaf(xB.w, wv.z, A[7].z); A[7].w = fmaf(xB.w, wv.w, A[7].w); }

__global__ __launch_bounds__(256) void proj_kernel(
    const float* __restrict__ x,
    const float* __restrict__ Wq, const float* __restrict__ bq,
    const float* __restrict__ Wk, const float* __restrict__ bk,
    const float* __restrict__ Wv, const float* __restrict__ bv,
    const float* __restrict__ we, float* __restrict__ wb,
    float* __restrict__ q, float* __restrict__ v, float4* __restrict__ kvT)
{
    __shared__ float  xs[E][8];          // [e][row]; wave-uniform e -> broadcast
    __shared__ float4 red[8][4][64];     // [row][wave][lane]

    const int t    = threadIdx.x;
    const int lane = t & 63;
    const int rg   = t >> 6;             // wave id = K-slice id
    const int type = blockIdx.x / 192;   // 0: q   1: merged k&v
    const int bid  = blockIdx.x % 192;
    const int ct   = bid >> 6;
    const int rt   = bid & 63;
    const int r0   = rt * 8;
    const int c    = ct * 256 + lane * 4;

    // one block prescales wb = 0.495*we (consumed by energy_kernel)
    if (blockIdx.x == 0 && t < H4) {
        float4 w = ((const float4*)we)[t];
        w.x *= 0.495f; w.y *= 0.495f; w.z *= 0.495f; w.w *= 0.495f;
        ((float4*)wb)[t] = w;
    }

    // stage x[r0..r0+7][e] as xs[e][r] (thread t = e index)
    {
        float4 lo, hi;
        lo.x = x[(r0 + 0) * E + t]; lo.y = x[(r0 + 1) * E + t];
        lo.z = x[(r0 + 2) * E + t]; lo.w = x[(r0 + 3) * E + t];
        hi.x = x[(r0 + 4) * E + t]; hi.y = x[(r0 + 5) * E + t];
        hi.z = x[(r0 + 6) * E + t]; hi.w = x[(r0 + 7) * E + t];
        *(float4*)&xs[t][0] = lo;
        *(float4*)&xs[t][4] = hi;
    }
    __syncthreads();

    const int e0 = rg * 64;

    if (type == 0) {
        float4 A[8] = {};
        const float4* Wp = (const float4*)(Wq + c);
        float4 w0 = Wp[(e0 + 0) * H4], w1 = Wp[(e0 + 1) * H4];
        float4 w2 = Wp[(e0 + 2) * H4], w3 = Wp[(e0 + 3) * H4];
        int e = e0;
        #pragma unroll 1
        for (; e < e0 + 60; e += 4) {
            float4 n0 = Wp[(e + 4) * H4], n1 = Wp[(e + 5) * H4];
            float4 n2 = Wp[(e + 6) * H4], n3 = Wp[(e + 7) * H4];
            PROJ_STEP(e    , w0, A);
            PROJ_STEP(e + 1, w1, A);
            PROJ_STEP(e + 2, w2, A);
            PROJ_STEP(e + 3, w3, A);
            w0 = n0; w1 = n1; w2 = n2; w3 = n3;
        }
        PROJ_STEP(e    , w0, A);
        PROJ_STEP(e + 1, w1, A);
        PROJ_STEP(e + 2, w2, A);
        PROJ_STEP(e + 3, w3, A);

        #pragma unroll
        for (int r = 0; r < 8; ++r) red[r][rg][lane] = A[r];
        __syncthreads();
        const float4 bias = *(const float4*)(bq + c);
        #pragma unroll
        for (int ri = 0; ri < 2; ++ri) {
            const int r = 2 * rg + ri;
            const float4 p0 = red[r][0][lane], p1 = red[r][1][lane];
            const float4 p2 = red[r][2][lane], p3 = red[r][3][lane];
            float4 s;
            s.x = ((p0.x + p1.x) + (p2.x + p3.x)) + bias.x;
            s.y = ((p0.y + p1.y) + (p2.y + p3.y)) + bias.y;
            s.z = ((p0.z + p1.z) + (p2.z + p3.z)) + bias.z;
            s.w = ((p0.w + p1.w) + (p2.w + p3.w)) + bias.w;
            *(float4*)(q + (size_t)(r0 + r) * H + c) = s;
        }
    } else {
        float4 AK[8] = {}, AV[8] = {};
        const float4* Kp = (const float4*)(Wk + c);
        const float4* Vp = (const float4*)(Wv + c);
        float4 k0 = Kp[(e0 + 0) * H4], k1 = Kp[(e0 + 1) * H4];
        float4 u0 = Vp[(e0 + 0) * H4], u1 = Vp[(e0 + 1) * H4];
        int e = e0;
        #pragma unroll 1
        for (; e < e0 + 62; e += 2) {
            float4 nk0 = Kp[(e + 2) * H4], nk1 = Kp[(e + 3) * H4];
            float4 nu0 = Vp[(e + 2) * H4], nu1 = Vp[(e + 3) * H4];
            PROJ_STEP(e    , k0, AK);
            PROJ_STEP(e    , u0, AV);
            PROJ_STEP(e + 1, k1, AK);
            PROJ_STEP(e + 1, u1, AV);
            k0 = nk0; k1 = nk1; u0 = nu0; u1 = nu1;
        }
        PROJ_STEP(e    , k0, AK);
        PROJ_STEP(e    , u0, AV);
        PROJ_STEP(e + 1, k1, AK);
        PROJ_STEP(e + 1, u1, AV);

        // pass 1: reduce v-partials, store v (biased), keep per-thread copy
        #pragma unroll
        for (int r = 0; r < 8; ++r) red[r][rg][lane] = AV[r];
        __syncthreads();
        const float4 bv4 = *(const float4*)(bv + c);
        const float4 bk4 = *(const float4*)(bk + c);
        float4 vs[2];
        #pragma unroll
        for (int ri = 0; ri < 2; ++ri) {
            const int r = 2 * rg + ri;
            const float4 p0 = red[r][0][lane], p1 = red[r][1][lane];
            const float4 p2 = red[r][2][lane], p3 = red[r][3][lane];
            float4 s;
            s.x = ((p0.x + p1.x) + (p2.x + p3.x)) + bv4.x;
            s.y = ((p0.y + p1.y) + (p2.y + p3.y)) + bv4.y;
            s.z = ((p0.z + p1.z) + (p2.z + p3.z)) + bv4.z;
            s.w = ((p0.w + p1.w) + (p2.w + p3.w)) + bv4.w;
            vs[ri] = s;
            *(float4*)(v + (size_t)(r0 + r) * H + c) = s;
        }
        __syncthreads();   // red reuse hazard

        // pass 2: reduce k-partials, kvT = ksum + (vsum+bv) + bk
        #pragma unroll
        for (int r = 0; r < 8; ++r) red[r][rg][lane] = AK[r];
        __syncthreads();
        #pragma unroll
        for (int ri = 0; ri < 2; ++ri) {
            const int r = 2 * rg + ri;
            const float4 p0 = red[r][0][lane], p1 = red[r][1][lane];
            const float4 p2 = red[r][2][lane], p3 = red[r][3][lane];
            float4 s;
            s.x = ((p0.x + p1.x) + (p2.x + p3.x)) + bk4.x + vs[ri].x;
            s.y = ((p0.y + p1.y) + (p2.y + p3.y)) + bk4.y + vs[ri].y;
            s.z = ((p0.z + p1.z) + (p2.z + p3.z)) + bk4.z + vs[ri].z;
            s.w = ((p0.w + p1.w) + (p2.w + p3.w)) + bk4.w + vs[ri].w;
            const int row = r0 + r;
            const int bb = row >> 8, n = row & 255;
            kvT[((size_t)bb * H4 + (c >> 2)) * N + n] = s;
        }
    }
}
#undef PROJ_STEP

// ---------------------------------------------------------------------------
// Energy via the identity  leaky_relu(s) = 0.505 s + 0.495 |s|:
//   energy[i,j] = row_const(i) + (0.505/0.495)*dot(kv_j, wb) + sum_h wb_h*|q+kv|
// with wb = 0.495*we. row_const is dropped (softmax shift-invariance).
// Block = 8 q-rows x 64 j, 512 threads as (hq = t>>5 in 0..15, jl = t&31),
// each thread handles TWO j columns (jl, jl+32): halves broadcast LDS reads
// per FMA. Elementwise cost: 1 v_add + 1 v_fma(|s| src-modifier) = 2 VALU.
// kacc (dot(kv,wb) partial) is folded into the per-hq partials before the
// pE reduce, so the cross-hq sum yields abs-part + KS*dot in one pass.
// ---------------------------------------------------------------------------
__global__ __launch_bounds__(512) void energy_kernel(
    const float* __restrict__ q, const float4* __restrict__ kvT,
    const float* __restrict__ wb, float* __restrict__ eout)
{
    __shared__ float qs[8][H];        // 24 KB
    __shared__ float wbs[H];          //  3 KB
    __shared__ float pE[8][16][64];   // [row][hq][j], 32 KB

    const int t    = threadIdx.x;
    const int jl   = t & 31;               // 0..31
    const int hq   = t >> 5;               // 0..15 (two per wave; bank-phase 16 in qs -> conflict-free)
    const int row0 = (blockIdx.x >> 2) * 8;
    const int j0   = (blockIdx.x & 3) * 64;
    const int b    = row0 >> 8;

    {
        float4* qs4 = (float4*)qs;
        const float4* qg = (const float4*)(q + (size_t)row0 * H);   // 8 contiguous rows
        #pragma unroll
        for (int i = 0; i < 3; ++i) qs4[t + 512 * i] = qg[t + 512 * i];
        if (t < H4) ((float4*)wbs)[t] = ((const float4*)wb)[t];
    }
    __syncthreads();

    const float4* kv0 = kvT + (size_t)b * H4 * N + (j0 + jl);   // stream 1 at +32
    const int base = hq * 12;                                   // 12 f4-idx per thread

    float acc0[8] = {0,0,0,0,0,0,0,0};
    float acc1[8] = {0,0,0,0,0,0,0,0};
    float4 ka0 = {0,0,0,0}, ka1 = {0,0,0,0};

#define ESTEP2(idx, u0_, u1_)                                                   \
    { const float4 wb4 = *(const float4*)&wbs[(idx) * 4];                       \
      ka0.x = fmaf(u0_.x, wb4.x, ka0.x); ka0.y = fmaf(u0_.y, wb4.y, ka0.y);     \
      ka0.z = fmaf(u0_.z, wb4.z, ka0.z); ka0.w = fmaf(u0_.w, wb4.w, ka0.w);     \
      ka1.x = fmaf(u1_.x, wb4.x, ka1.x); ka1.y = fmaf(u1_.y, wb4.y, ka1.y);     \
      ka1.z = fmaf(u1_.z, wb4.z, ka1.z); ka1.w = fmaf(u1_.w, wb4.w, ka1.w);     \
      _Pragma("unroll")                                                         \
      for (int r = 0; r < 8; ++r) {                                             \
          const float4 qa = *(const float4*)&qs[r][(idx) * 4];                  \
          float s;                                                              \
          s = qa.x + u0_.x; acc0[r] = fmaf(__builtin_fabsf(s), wb4.x, acc0[r]); \
          s = qa.x + u1_.x; acc1[r] = fmaf(__builtin_fabsf(s), wb4.x, acc1[r]); \
          s = qa.y + u0_.y; acc0[r] = fmaf(__builtin_fabsf(s), wb4.y, acc0[r]); \
          s = qa.y + u1_.y; acc1[r] = fmaf(__builtin_fabsf(s), wb4.y, acc1[r]); \
          s = qa.z + u0_.z; acc0[r] = fmaf(__builtin_fabsf(s), wb4.z, acc0[r]); \
          s = qa.z + u1_.z; acc1[r] = fmaf(__builtin_fabsf(s), wb4.z, acc1[r]); \
          s = qa.w + u0_.w; acc0[r] = fmaf(__builtin_fabsf(s), wb4.w, acc0[r]); \
          s = qa.w + u1_.w; acc1[r] = fmaf(__builtin_fabsf(s), wb4.w, acc1[r]); \
      } }

    float4 a0 = kv0[(base + 0) * N],      a1 = kv0[(base + 1) * N];
    float4 c0 = kv0[(base + 0) * N + 32], c1 = kv0[(base + 1) * N + 32];
    int it = 0;
    #pragma unroll 1
    for (; it < 10; it += 2) {
        float4 na0 = kv0[(base + it + 2) * N],      na1 = kv0[(base + it + 3) * N];
        float4 nc0 = kv0[(base + it + 2) * N + 32], nc1 = kv0[(base + it + 3) * N + 32];
        ESTEP2(base + it    , a0, c0);
        ESTEP2(base + it + 1, a1, c1);
        a0 = na0; a1 = na1; c0 = nc0; c1 = nc1;
    }
    ESTEP2(base + 10, a0, c0);
    ESTEP2(base + 11, a1, c1);
#undef ESTEP2

    // fold KS*dot(kv,wb) partials into per-hq accs; cross-hq sum completes both
    const float KS = 0.505f / 0.495f;
    const float k0s = KS * ((ka0.x + ka0.y) + (ka0.z + ka0.w));
    const float k1s = KS * ((ka1.x + ka1.y) + (ka1.z + ka1.w));
    #pragma unroll
    for (int r = 0; r < 8; ++r) {
        pE[r][hq][jl]      = acc0[r] + k0s;
        pE[r][hq][jl + 32] = acc1[r] + k1s;
    }
    __syncthreads();

    const int rr = t >> 6, jc = t & 63;
    float ev = 0.f;
    #pragma unroll
    for (int k = 0; k < 16; ++k) ev += pE[rr][k][jc];
    eout[(size_t)(row0 + rr) * N + j0 + jc] = ev;
}

// ---------------------------------------------------------------------------
// Softmax + PV: unchanged (softmax is invariant to the per-row shift the
// energy kernel now omits). block = 8 i-rows x 128 h, 256 threads, 384 blocks.
// ---------------------------------------------------------------------------
#define PSTEP(aj, vv, Am) \
    Am.x = fmaf(aj, vv.x, Am.x); Am.y = fmaf(aj, vv.y, Am.y); \
    Am.z = fmaf(aj, vv.z, Am.z); Am.w = fmaf(aj, vv.w, Am.w);

__global__ __launch_bounds__(256) void pv_kernel(
    const float* __restrict__ eout, const float* __restrict__ v,
    float* __restrict__ out)
{
    __shared__ float es[8][256];     // energies -> p values
    __shared__ float inv_s[8];

    const int t   = threadIdx.x;
    const int b   = blockIdx.x / 192;
    const int r_  = blockIdx.x % 192;
    const int it_ = r_ / 6;          // 0..31 i-tile
    const int ht  = r_ % 6;          // 0..5  h-tile (128 h)
    const int i0  = it_ * 8;
    const int h4l = t & 31;
    const int il  = t >> 5;          // 0..7

    {
        float4* es4 = (float4*)es;
        const float4* ep = (const float4*)(eout + (size_t)(b * 256 + i0) * N);
        es4[t]       = ep[t];
        es4[t + 256] = ep[t + 256];
    }
    __syncthreads();

    // in-wave softmax: wave wv owns rows 2wv, 2wv+1
    const int wv = t >> 6, ln = t & 63;
    #pragma unroll
    for (int rr = 0; rr < 2; ++rr) {
        const int row = wv * 2 + rr;
        const float4 evv = ((const float4*)es[row])[ln];
        float m = fmaxf(fmaxf(evv.x, evv.y), fmaxf(evv.z, evv.w));
        #pragma unroll
        for (int off = 1; off < 64; off <<= 1) m = fmaxf(m, __shfl_xor(m, off));
        float4 p;
        p.x = __expf(evv.x - m); p.y = __expf(evv.y - m);
        p.z = __expf(evv.z - m); p.w = __expf(evv.w - m);
        float s = (p.x + p.y) + (p.z + p.w);
        #pragma unroll
        for (int off = 1; off < 64; off <<= 1) s += __shfl_xor(s, off);
        ((float4*)es[row])[ln] = p;
        if (ln == 0) inv_s[row] = 1.0f / s;
    }
    __syncthreads();

    // PV
    const float4* vp = (const float4*)(v + (size_t)(b * 256) * H + ht * 128) + h4l;
    const float4* a4 = (const float4*)es[il];

    float4 P = {0.f, 0.f, 0.f, 0.f}, Q = P;
    float4 av = a4[0];
    float4 v0 = vp[0], v1 = vp[H4], v2 = vp[2 * H4], v3 = vp[3 * H4];
    int j4 = 0;
    #pragma unroll 1
    for (; j4 < 63; ++j4) {
        const float4 nav = a4[j4 + 1];
        const int jb = 4 * j4 + 4;
        float4 n0 = vp[(jb + 0) * H4], n1 = vp[(jb + 1) * H4];
        float4 n2 = vp[(jb + 2) * H4], n3 = vp[(jb + 3) * H4];
        PSTEP(av.x, v0, P); PSTEP(av.y, v1, Q);
        PSTEP(av.z, v2, P); PSTEP(av.w, v3, Q);
        av = nav;
        v0 = n0; v1 = n1; v2 = n2; v3 = n3;
    }
    PSTEP(av.x, v0, P); PSTEP(av.y, v1, Q);
    PSTEP(av.z, v2, P); PSTEP(av.w, v3, Q);

    const float is = inv_s[il];
    float4 R;
    R.x = (P.x + Q.x) * is; R.y = (P.y + Q.y) * is;
    R.z = (P.z + Q.z) * is; R.w = (P.w + Q.w) * is;
    *(float4*)(out + (size_t)(b * 256 + i0 + il) * H + ht * 128 + h4l * 4) = R;
}

extern "C" void kernel_launch(void* const* d_in, const int* in_sizes, int n_in,
                              void* d_out, int out_size, void* d_ws, size_t ws_size,
                              hipStream_t stream) {
    const float* x  = (const float*)d_in[0];
    const float* Wq = (const float*)d_in[1];
    const float* bq = (const float*)d_in[2];
    const float* Wk = (const float*)d_in[3];
    const float* bk = (const float*)d_in[4];
    const float* Wv = (const float*)d_in[5];
    const float* bv = (const float*)d_in[6];
    const float* we = (const float*)d_in[7];
    float* out = (float*)d_out;

    float*  q    = (float*)d_ws;                 // [512][768]
    float*  v    = q + B * N * H;                // [512][768]
    float4* kvT  = (float4*)(v + B * N * H);     // [B][H4][N]
    float*  eout = (float*)(kvT + B * H4 * N);   // [512][256] shifted energies
    float*  wb   = eout + B * N * N;             // [768] = 0.495*we

    proj_kernel<<<384, 256, 0, stream>>>(x, Wq, bq, Wk, bk, Wv, bv, we, wb, q, v, kvT);
    energy_kernel<<<256, 512, 0, stream>>>(q, kvT, wb, eout);
    pv_kernel<<<384, 256, 0, stream>>>(eout, v, out);
}

// Round 2
// 55.418 us; speedup vs baseline: 1.0462x; 1.0229x over previous
//
#include <hip/hip_runtime.h>

#define B 2
#define N 256
#define E 256
#define H 768
#define H4 (H / 4)

// ---------------------------------------------------------------------------
// Projection GEMM, split-K: 2 block types, 384 blocks, LPT-ordered.
//   blockIdx   0..191 (type 1, HEAVY, 2 work-units): dual accumulators ->
//              v = x@Wv+bv AND kvT = (x@Wk + x@Wv + bk + bv)^T
//   blockIdx 192..383 (type 0, light, 1 work-unit): q = x@Wq + bq
// Heavy blocks dispatch first (LPT) so second-wave blocks on busy CUs are
// light ones: critical path ~3 units instead of worst-case 5.
// W L2 traffic: 144 MB (Wq once, Wk once, Wv once — the 8-row-tile floor).
// Block 0 also prescales wb[h] = 0.495*we[h] for the energy kernel.
// ---------------------------------------------------------------------------
#define PROJ_STEP(ee, wv, A)                                                  \
    { const float4 xA = *(const float4*)&xs[ee][0];                           \
      const float4 xB = *(const float4*)&xs[ee][4];                           \
      A[0].x = fmaf(xA.x, wv.x, A[0].x); A[0].y = fmaf(xA.x, wv.y, A[0].y);   \
      A[0].z = fmaf(xA.x, wv.z, A[0].z); A[0].w = fmaf(xA.x, wv.w, A[0].w);   \
      A[1].x = fmaf(xA.y, wv.x, A[1].x); A[1].y = fmaf(xA.y, wv.y, A[1].y);   \
      A[1].z = fmaf(xA.y, wv.z, A[1].z); A[1].w = fmaf(xA.y, wv.w, A[1].w);   \
      A[2].x = fmaf(xA.z, wv.x, A[2].x); A[2].y = fmaf(xA.z, wv.y, A[2].y);   \
      A[2].z = fmaf(xA.z, wv.z, A[2].z); A[2].w = fmaf(xA.z, wv.w, A[2].w);   \
      A[3].x = fmaf(xA.w, wv.x, A[3].x); A[3].y = fmaf(xA.w, wv.y, A[3].y);   \
      A[3].z = fmaf(xA.w, wv.z, A[3].z); A[3].w = fmaf(xA.w, wv.w, A[3].w);   \
      A[4].x = fmaf(xB.x, wv.x, A[4].x); A[4].y = fmaf(xB.x, wv.y, A[4].y);   \
      A[4].z = fmaf(xB.x, wv.z, A[4].z); A[4].w = fmaf(xB.x, wv.w, A[4].w);   \
      A[5].x = fmaf(xB.y, wv.x, A[5].x); A[5].y = fmaf(xB.y, wv.y, A[5].y);   \
      A[5].z = fmaf(xB.y, wv.z, A[5].z); A[5].w = fmaf(xB.y, wv.w, A[5].w);   \
      A[6].x = fmaf(xB.z, wv.x, A[6].x); A[6].y = fmaf(xB.z, wv.y, A[6].y);   \
      A[6].z = fmaf(xB.z, wv.z, A[6].z); A[6].w = fmaf(xB.z, wv.w, A[6].w);   \
      A[7].x = fmaf(xB.w, wv.x, A[7].x); A[7].y = fmaf(xB.w, wv.y, A[7].y);   \
      A[7].z = fmaf(xB.w, wv.z, A[7].z); A[7].w = fmaf(xB.w, wv.w, A[7].w); }

__global__ __launch_bounds__(256) void proj_kernel(
    const float* __restrict__ x,
    const float* __restrict__ Wq, const float* __restrict__ bq,
    const float* __restrict__ Wk, const float* __restrict__ bk,
    const float* __restrict__ Wv, const float* __restrict__ bv,
    const float* __restrict__ we, float* __restrict__ wb,
    float* __restrict__ q, float* __restrict__ v, float4* __restrict__ kvT)
{
    __shared__ float  xs[E][8];          // [e][row]; wave-uniform e -> broadcast
    __shared__ float4 red[8][4][64];     // [row][wave][lane]

    const int t    = threadIdx.x;
    const int lane = t & 63;
    const int rg   = t >> 6;             // wave id = K-slice id
    const int type = (blockIdx.x < 192) ? 1 : 0;   // LPT: heavy first
    const int bid  = blockIdx.x % 192;
    const int ct   = bid >> 6;
    const int rt   = bid & 63;
    const int r0   = rt * 8;
    const int c    = ct * 256 + lane * 4;

    // one block prescales wb = 0.495*we (consumed by energy_kernel)
    if (blockIdx.x == 0 && t < H4) {
        float4 w = ((const float4*)we)[t];
        w.x *= 0.495f; w.y *= 0.495f; w.z *= 0.495f; w.w *= 0.495f;
        ((float4*)wb)[t] = w;
    }

    // stage x[r0..r0+7][e] as xs[e][r] (thread t = e index)
    {
        float4 lo, hi;
        lo.x = x[(r0 + 0) * E + t]; lo.y = x[(r0 + 1) * E + t];
        lo.z = x[(r0 + 2) * E + t]; lo.w = x[(r0 + 3) * E + t];
        hi.x = x[(r0 + 4) * E + t]; hi.y = x[(r0 + 5) * E + t];
        hi.z = x[(r0 + 6) * E + t]; hi.w = x[(r0 + 7) * E + t];
        *(float4*)&xs[t][0] = lo;
        *(float4*)&xs[t][4] = hi;
    }
    __syncthreads();

    const int e0 = rg * 64;

    if (type == 0) {
        float4 A[8] = {};
        const float4* Wp = (const float4*)(Wq + c);
        float4 w0 = Wp[(e0 + 0) * H4], w1 = Wp[(e0 + 1) * H4];
        float4 w2 = Wp[(e0 + 2) * H4], w3 = Wp[(e0 + 3) * H4];
        int e = e0;
        #pragma unroll 1
        for (; e < e0 + 60; e += 4) {
            float4 n0 = Wp[(e + 4) * H4], n1 = Wp[(e + 5) * H4];
            float4 n2 = Wp[(e + 6) * H4], n3 = Wp[(e + 7) * H4];
            PROJ_STEP(e    , w0, A);
            PROJ_STEP(e + 1, w1, A);
            PROJ_STEP(e + 2, w2, A);
            PROJ_STEP(e + 3, w3, A);
            w0 = n0; w1 = n1; w2 = n2; w3 = n3;
        }
        PROJ_STEP(e    , w0, A);
        PROJ_STEP(e + 1, w1, A);
        PROJ_STEP(e + 2, w2, A);
        PROJ_STEP(e + 3, w3, A);

        #pragma unroll
        for (int r = 0; r < 8; ++r) red[r][rg][lane] = A[r];
        __syncthreads();
        const float4 bias = *(const float4*)(bq + c);
        #pragma unroll
        for (int ri = 0; ri < 2; ++ri) {
            const int r = 2 * rg + ri;
            const float4 p0 = red[r][0][lane], p1 = red[r][1][lane];
            const float4 p2 = red[r][2][lane], p3 = red[r][3][lane];
            float4 s;
            s.x = ((p0.x + p1.x) + (p2.x + p3.x)) + bias.x;
            s.y = ((p0.y + p1.y) + (p2.y + p3.y)) + bias.y;
            s.z = ((p0.z + p1.z) + (p2.z + p3.z)) + bias.z;
            s.w = ((p0.w + p1.w) + (p2.w + p3.w)) + bias.w;
            *(float4*)(q + (size_t)(r0 + r) * H + c) = s;
        }
    } else {
        float4 AK[8] = {}, AV[8] = {};
        const float4* Kp = (const float4*)(Wk + c);
        const float4* Vp = (const float4*)(Wv + c);
        float4 k0 = Kp[(e0 + 0) * H4], k1 = Kp[(e0 + 1) * H4];
        float4 u0 = Vp[(e0 + 0) * H4], u1 = Vp[(e0 + 1) * H4];
        int e = e0;
        #pragma unroll 1
        for (; e < e0 + 62; e += 2) {
            float4 nk0 = Kp[(e + 2) * H4], nk1 = Kp[(e + 3) * H4];
            float4 nu0 = Vp[(e + 2) * H4], nu1 = Vp[(e + 3) * H4];
            PROJ_STEP(e    , k0, AK);
            PROJ_STEP(e    , u0, AV);
            PROJ_STEP(e + 1, k1, AK);
            PROJ_STEP(e + 1, u1, AV);
            k0 = nk0; k1 = nk1; u0 = nu0; u1 = nu1;
        }
        PROJ_STEP(e    , k0, AK);
        PROJ_STEP(e    , u0, AV);
        PROJ_STEP(e + 1, k1, AK);
        PROJ_STEP(e + 1, u1, AV);

        // pass 1: reduce v-partials, store v (biased), keep per-thread copy
        #pragma unroll
        for (int r = 0; r < 8; ++r) red[r][rg][lane] = AV[r];
        __syncthreads();
        const float4 bv4 = *(const float4*)(bv + c);
        const float4 bk4 = *(const float4*)(bk + c);
        float4 vs[2];
        #pragma unroll
        for (int ri = 0; ri < 2; ++ri) {
            const int r = 2 * rg + ri;
            const float4 p0 = red[r][0][lane], p1 = red[r][1][lane];
            const float4 p2 = red[r][2][lane], p3 = red[r][3][lane];
            float4 s;
            s.x = ((p0.x + p1.x) + (p2.x + p3.x)) + bv4.x;
            s.y = ((p0.y + p1.y) + (p2.y + p3.y)) + bv4.y;
            s.z = ((p0.z + p1.z) + (p2.z + p3.z)) + bv4.z;
            s.w = ((p0.w + p1.w) + (p2.w + p3.w)) + bv4.w;
            vs[ri] = s;
            *(float4*)(v + (size_t)(r0 + r) * H + c) = s;
        }
        __syncthreads();   // red reuse hazard

        // pass 2: reduce k-partials, kvT = ksum + (vsum+bv) + bk
        #pragma unroll
        for (int r = 0; r < 8; ++r) red[r][rg][lane] = AK[r];
        __syncthreads();
        #pragma unroll
        for (int ri = 0; ri < 2; ++ri) {
            const int r = 2 * rg + ri;
            const float4 p0 = red[r][0][lane], p1 = red[r][1][lane];
            const float4 p2 = red[r][2][lane], p3 = red[r][3][lane];
            float4 s;
            s.x = ((p0.x + p1.x) + (p2.x + p3.x)) + bk4.x + vs[ri].x;
            s.y = ((p0.y + p1.y) + (p2.y + p3.y)) + bk4.y + vs[ri].y;
            s.z = ((p0.z + p1.z) + (p2.z + p3.z)) + bk4.z + vs[ri].z;
            s.w = ((p0.w + p1.w) + (p2.w + p3.w)) + bk4.w + vs[ri].w;
            const int row = r0 + r;
            const int bb = row >> 8, n = row & 255;
            kvT[((size_t)bb * H4 + (c >> 2)) * N + n] = s;
        }
    }
}
#undef PROJ_STEP

// ---------------------------------------------------------------------------
// Energy via the identity  leaky_relu(s) = 0.505 s + 0.495 |s|:
//   energy[i,j] = row_const(i) + (0.505/0.495)*dot(kv_j, wb) + sum_h wb_h*|q+kv|
// with wb = 0.495*we. row_const is dropped (softmax shift-invariance).
// Unchanged from R1 (est. ~2.8 us, at the 2-VALU/elem floor).
// ---------------------------------------------------------------------------
__global__ __launch_bounds__(512) void energy_kernel(
    const float* __restrict__ q, const float4* __restrict__ kvT,
    const float* __restrict__ wb, float* __restrict__ eout)
{
    __shared__ float qs[8][H];        // 24 KB
    __shared__ float wbs[H];          //  3 KB
    __shared__ float pE[8][16][64];   // [row][hq][j], 32 KB

    const int t    = threadIdx.x;
    const int jl   = t & 31;               // 0..31
    const int hq   = t >> 5;               // 0..15
    const int row0 = (blockIdx.x >> 2) * 8;
    const int j0   = (blockIdx.x & 3) * 64;
    const int b    = row0 >> 8;

    {
        float4* qs4 = (float4*)qs;
        const float4* qg = (const float4*)(q + (size_t)row0 * H);   // 8 contiguous rows
        #pragma unroll
        for (int i = 0; i < 3; ++i) qs4[t + 512 * i] = qg[t + 512 * i];
        if (t < H4) ((float4*)wbs)[t] = ((const float4*)wb)[t];
    }
    __syncthreads();

    const float4* kv0 = kvT + (size_t)b * H4 * N + (j0 + jl);   // stream 1 at +32
    const int base = hq * 12;                                   // 12 f4-idx per thread

    float acc0[8] = {0,0,0,0,0,0,0,0};
    float acc1[8] = {0,0,0,0,0,0,0,0};
    float4 ka0 = {0,0,0,0}, ka1 = {0,0,0,0};

#define ESTEP2(idx, u0_, u1_)                                                   \
    { const float4 wb4 = *(const float4*)&wbs[(idx) * 4];                       \
      ka0.x = fmaf(u0_.x, wb4.x, ka0.x); ka0.y = fmaf(u0_.y, wb4.y, ka0.y);     \
      ka0.z = fmaf(u0_.z, wb4.z, ka0.z); ka0.w = fmaf(u0_.w, wb4.w, ka0.w);     \
      ka1.x = fmaf(u1_.x, wb4.x, ka1.x); ka1.y = fmaf(u1_.y, wb4.y, ka1.y);     \
      ka1.z = fmaf(u1_.z, wb4.z, ka1.z); ka1.w = fmaf(u1_.w, wb4.w, ka1.w);     \
      _Pragma("unroll")                                                         \
      for (int r = 0; r < 8; ++r) {                                             \
          const float4 qa = *(const float4*)&qs[r][(idx) * 4];                  \
          float s;                                                              \
          s = qa.x + u0_.x; acc0[r] = fmaf(__builtin_fabsf(s), wb4.x, acc0[r]); \
          s = qa.x + u1_.x; acc1[r] = fmaf(__builtin_fabsf(s), wb4.x, acc1[r]); \
          s = qa.y + u0_.y; acc0[r] = fmaf(__builtin_fabsf(s), wb4.y, acc0[r]); \
          s = qa.y + u1_.y; acc1[r] = fmaf(__builtin_fabsf(s), wb4.y, acc1[r]); \
          s = qa.z + u0_.z; acc0[r] = fmaf(__builtin_fabsf(s), wb4.z, acc0[r]); \
          s = qa.z + u1_.z; acc1[r] = fmaf(__builtin_fabsf(s), wb4.z, acc1[r]); \
          s = qa.w + u0_.w; acc0[r] = fmaf(__builtin_fabsf(s), wb4.w, acc0[r]); \
          s = qa.w + u1_.w; acc1[r] = fmaf(__builtin_fabsf(s), wb4.w, acc1[r]); \
      } }

    float4 a0 = kv0[(base + 0) * N],      a1 = kv0[(base + 1) * N];
    float4 c0 = kv0[(base + 0) * N + 32], c1 = kv0[(base + 1) * N + 32];
    int it = 0;
    #pragma unroll 1
    for (; it < 10; it += 2) {
        float4 na0 = kv0[(base + it + 2) * N],      na1 = kv0[(base + it + 3) * N];
        float4 nc0 = kv0[(base + it + 2) * N + 32], nc1 = kv0[(base + it + 3) * N + 32];
        ESTEP2(base + it    , a0, c0);
        ESTEP2(base + it + 1, a1, c1);
        a0 = na0; a1 = na1; c0 = nc0; c1 = nc1;
    }
    ESTEP2(base + 10, a0, c0);
    ESTEP2(base + 11, a1, c1);
#undef ESTEP2

    const float KS = 0.505f / 0.495f;
    const float k0s = KS * ((ka0.x + ka0.y) + (ka0.z + ka0.w));
    const float k1s = KS * ((ka1.x + ka1.y) + (ka1.z + ka1.w));
    #pragma unroll
    for (int r = 0; r < 8; ++r) {
        pE[r][hq][jl]      = acc0[r] + k0s;
        pE[r][hq][jl + 32] = acc1[r] + k1s;
    }
    __syncthreads();

    const int rr = t >> 6, jc = t & 63;
    float ev = 0.f;
    #pragma unroll
    for (int k = 0; k < 16; ++k) ev += pE[rr][k][jc];
    eout[(size_t)(row0 + rr) * N + j0 + jc] = ev;
}

// ---------------------------------------------------------------------------
// Softmax + PV: block = 16 i-rows x 64 h, 256 threads (il = t>>4, h4l = t&15),
// 384 blocks. 16-row amortization halves v L2 traffic: 48 -> 24 MB.
// Phase 1: load 16 energy rows to LDS (16 KB), wave wv softmaxes rows
// 4wv..4wv+3. Phase 2: out[i, 4h] = inv_s * sum_j p[j]*v[j,4h].
// ---------------------------------------------------------------------------
#define PSTEP(aj, vv, Am) \
    Am.x = fmaf(aj, vv.x, Am.x); Am.y = fmaf(aj, vv.y, Am.y); \
    Am.z = fmaf(aj, vv.z, Am.z); Am.w = fmaf(aj, vv.w, Am.w);

__global__ __launch_bounds__(256) void pv_kernel(
    const float* __restrict__ eout, const float* __restrict__ v,
    float* __restrict__ out)
{
    __shared__ float es[16][256];    // energies -> p values, 16 KB
    __shared__ float inv_s[16];

    const int t   = threadIdx.x;
    const int b   = blockIdx.x / 192;
    const int r_  = blockIdx.x % 192;
    const int it_ = r_ / 12;         // 0..15 i-tile (16 rows)
    const int ht  = r_ % 12;         // 0..11 h-tile (64 h)
    const int i0  = it_ * 16;
    const int h4l = t & 15;
    const int il  = t >> 4;          // 0..15

    {
        float4* es4 = (float4*)es;
        const float4* ep = (const float4*)(eout + (size_t)(b * 256 + i0) * N);
        #pragma unroll
        for (int k = 0; k < 4; ++k) es4[t + 256 * k] = ep[t + 256 * k];
    }
    __syncthreads();

    // in-wave softmax: wave wv owns rows 4wv..4wv+3
    const int wv = t >> 6, ln = t & 63;
    #pragma unroll
    for (int rr = 0; rr < 4; ++rr) {
        const int row = wv * 4 + rr;
        const float4 evv = ((const float4*)es[row])[ln];
        float m = fmaxf(fmaxf(evv.x, evv.y), fmaxf(evv.z, evv.w));
        #pragma unroll
        for (int off = 1; off < 64; off <<= 1) m = fmaxf(m, __shfl_xor(m, off));
        float4 p;
        p.x = __expf(evv.x - m); p.y = __expf(evv.y - m);
        p.z = __expf(evv.z - m); p.w = __expf(evv.w - m);
        float s = (p.x + p.y) + (p.z + p.w);
        #pragma unroll
        for (int off = 1; off < 64; off <<= 1) s += __shfl_xor(s, off);
        ((float4*)es[row])[ln] = p;
        if (ln == 0) inv_s[row] = 1.0f / s;
    }
    __syncthreads();

    // PV
    const float4* vp = (const float4*)(v + (size_t)(b * 256) * H + ht * 64) + h4l;
    const float4* a4 = (const float4*)es[il];

    float4 P = {0.f, 0.f, 0.f, 0.f}, Q = P;
    float4 av = a4[0];
    float4 v0 = vp[0], v1 = vp[H4], v2 = vp[2 * H4], v3 = vp[3 * H4];
    int j4 = 0;
    #pragma unroll 1
    for (; j4 < 63; ++j4) {
        const float4 nav = a4[j4 + 1];
        const int jb = 4 * j4 + 4;
        float4 n0 = vp[(jb + 0) * H4], n1 = vp[(jb + 1) * H4];
        float4 n2 = vp[(jb + 2) * H4], n3 = vp[(jb + 3) * H4];
        PSTEP(av.x, v0, P); PSTEP(av.y, v1, Q);
        PSTEP(av.z, v2, P); PSTEP(av.w, v3, Q);
        av = nav;
        v0 = n0; v1 = n1; v2 = n2; v3 = n3;
    }
    PSTEP(av.x, v0, P); PSTEP(av.y, v1, Q);
    PSTEP(av.z, v2, P); PSTEP(av.w, v3, Q);

    const float is = inv_s[il];
    float4 R;
    R.x = (P.x + Q.x) * is; R.y = (P.y + Q.y) * is;
    R.z = (P.z + Q.z) * is; R.w = (P.w + Q.w) * is;
    *(float4*)(out + (size_t)(b * 256 + i0 + il) * H + ht * 64 + h4l * 4) = R;
}

extern "C" void kernel_launch(void* const* d_in, const int* in_sizes, int n_in,
                              void* d_out, int out_size, void* d_ws, size_t ws_size,
                              hipStream_t stream) {
    const float* x  = (const float*)d_in[0];
    const float* Wq = (const float*)d_in[1];
    const float* bq = (const float*)d_in[2];
    const float* Wk = (const float*)d_in[3];
    const float* bk = (const float*)d_in[4];
    const float* Wv = (const float*)d_in[5];
    const float* bv = (const float*)d_in[6];
    const float* we = (const float*)d_in[7];
    float* out = (float*)d_out;

    float*  q    = (float*)d_ws;                 // [512][768]
    float*  v    = q + B * N * H;                // [512][768]
    float4* kvT  = (float4*)(v + B * N * H);     // [B][H4][N]
    float*  eout = (float*)(kvT + B * H4 * N);   // [512][256] shifted energies
    float*  wb   = eout + B * N * N;             // [768] = 0.495*we

    proj_kernel<<<384, 256, 0, stream>>>(x, Wq, bq, Wk, bk, Wv, bv, we, wb, q, v, kvT);
    energy_kernel<<<256, 512, 0, stream>>>(q, kvT, wb, eout);
    pv_kernel<<<384, 256, 0, stream>>>(eout, v, out);
}

// Round 3
// 55.077 us; speedup vs baseline: 1.0527x; 1.0062x over previous
//
#include <hip/hip_runtime.h>

#define B 2
#define N 256
#define E 256
#define H 768
#define H4 (H / 4)

// ---------------------------------------------------------------------------
// Projection GEMM, split-K: 8 rows x 128 cols blocks, 768 blocks, LPT order.
//   blockIdx   0..383 (HEAVY, 1 unit): dual acc -> v = x@Wv+bv AND
//              kvT = (x@Wk + x@Wv + bk + bv)^T
//   blockIdx 384..767 (light, 1/2 unit): q = x@Wq + bq
// Halved block granularity: critical path ~2.25-2.5 units (was 3).
// W L2 traffic unchanged at 144 MB (col splits don't duplicate W reads).
// K-split: 8 slices of 32 e (wave = 2 half-wave subslices).
// Block 0 also prescales wb[h] = 0.495*we[h] for the energy kernel.
// ---------------------------------------------------------------------------
#define PROJ_STEP(ee, wv, A)                                                  \
    { const float4 xA = *(const float4*)&xs[ee][0];                           \
      const float4 xB = *(const float4*)&xs[ee][4];                           \
      A[0].x = fmaf(xA.x, wv.x, A[0].x); A[0].y = fmaf(xA.x, wv.y, A[0].y);   \
      A[0].z = fmaf(xA.x, wv.z, A[0].z); A[0].w = fmaf(xA.x, wv.w, A[0].w);   \
      A[1].x = fmaf(xA.y, wv.x, A[1].x); A[1].y = fmaf(xA.y, wv.y, A[1].y);   \
      A[1].z = fmaf(xA.y, wv.z, A[1].z); A[1].w = fmaf(xA.y, wv.w, A[1].w);   \
      A[2].x = fmaf(xA.z, wv.x, A[2].x); A[2].y = fmaf(xA.z, wv.y, A[2].y);   \
      A[2].z = fmaf(xA.z, wv.z, A[2].z); A[2].w = fmaf(xA.z, wv.w, A[2].w);   \
      A[3].x = fmaf(xA.w, wv.x, A[3].x); A[3].y = fmaf(xA.w, wv.y, A[3].y);   \
      A[3].z = fmaf(xA.w, wv.z, A[3].z); A[3].w = fmaf(xA.w, wv.w, A[3].w);   \
      A[4].x = fmaf(xB.x, wv.x, A[4].x); A[4].y = fmaf(xB.x, wv.y, A[4].y);   \
      A[4].z = fmaf(xB.x, wv.z, A[4].z); A[4].w = fmaf(xB.x, wv.w, A[4].w);   \
      A[5].x = fmaf(xB.y, wv.x, A[5].x); A[5].y = fmaf(xB.y, wv.y, A[5].y);   \
      A[5].z = fmaf(xB.y, wv.z, A[5].z); A[5].w = fmaf(xB.y, wv.w, A[5].w);   \
      A[6].x = fmaf(xB.z, wv.x, A[6].x); A[6].y = fmaf(xB.z, wv.y, A[6].y);   \
      A[6].z = fmaf(xB.z, wv.z, A[6].z); A[6].w = fmaf(xB.z, wv.w, A[6].w);   \
      A[7].x = fmaf(xB.w, wv.x, A[7].x); A[7].y = fmaf(xB.w, wv.y, A[7].y);   \
      A[7].z = fmaf(xB.w, wv.z, A[7].z); A[7].w = fmaf(xB.w, wv.w, A[7].w); }

__global__ __launch_bounds__(256) void proj_kernel(
    const float* __restrict__ x,
    const float* __restrict__ Wq, const float* __restrict__ bq,
    const float* __restrict__ Wk, const float* __restrict__ bk,
    const float* __restrict__ Wv, const float* __restrict__ bv,
    const float* __restrict__ we, float* __restrict__ wb,
    float* __restrict__ q, float* __restrict__ v, float4* __restrict__ kvT)
{
    __shared__ float  xs[E][8];          // 8 KB; wave-uniform e -> broadcast
    __shared__ float4 red[8][8][32];     // [row][kslice][cl], 32 KB

    const int t     = threadIdx.x;
    const int lane  = t & 63;
    const int cl    = t & 31;                         // f4-col within 128-col tile
    const int ks    = ((t >> 6) << 1) | (lane >> 5);  // K-slice 0..7 (32 e each)
    const int heavy = (blockIdx.x < 384);             // LPT: heavy first
    const int bid   = heavy ? blockIdx.x : (blockIdx.x - 384);
    const int ct    = bid >> 6;          // 0..5 (128-col tiles)
    const int rt    = bid & 63;
    const int r0    = rt * 8;
    const int c     = ct * 128 + cl * 4;

    // one block prescales wb = 0.495*we (consumed by energy_kernel)
    if (blockIdx.x == 0 && t < H4) {
        float4 w = ((const float4*)we)[t];
        w.x *= 0.495f; w.y *= 0.495f; w.z *= 0.495f; w.w *= 0.495f;
        ((float4*)wb)[t] = w;
    }

    // stage x[r0..r0+7][e] as xs[e][r] (thread t = e index)
    {
        float4 lo, hi;
        lo.x = x[(r0 + 0) * E + t]; lo.y = x[(r0 + 1) * E + t];
        lo.z = x[(r0 + 2) * E + t]; lo.w = x[(r0 + 3) * E + t];
        hi.x = x[(r0 + 4) * E + t]; hi.y = x[(r0 + 5) * E + t];
        hi.z = x[(r0 + 6) * E + t]; hi.w = x[(r0 + 7) * E + t];
        *(float4*)&xs[t][0] = lo;
        *(float4*)&xs[t][4] = hi;
    }
    __syncthreads();

    const int e0 = ks * 32;
    const int orow = t >> 5;             // epilogue row 0..7

    if (!heavy) {
        float4 A[8] = {};
        const float4* Wp = (const float4*)(Wq + c);
        float4 w0 = Wp[(e0 + 0) * H4], w1 = Wp[(e0 + 1) * H4];
        float4 w2 = Wp[(e0 + 2) * H4], w3 = Wp[(e0 + 3) * H4];
        int e = e0;
        #pragma unroll 1
        for (; e < e0 + 28; e += 4) {
            float4 n0 = Wp[(e + 4) * H4], n1 = Wp[(e + 5) * H4];
            float4 n2 = Wp[(e + 6) * H4], n3 = Wp[(e + 7) * H4];
            PROJ_STEP(e    , w0, A);
            PROJ_STEP(e + 1, w1, A);
            PROJ_STEP(e + 2, w2, A);
            PROJ_STEP(e + 3, w3, A);
            w0 = n0; w1 = n1; w2 = n2; w3 = n3;
        }
        PROJ_STEP(e    , w0, A);
        PROJ_STEP(e + 1, w1, A);
        PROJ_STEP(e + 2, w2, A);
        PROJ_STEP(e + 3, w3, A);

        #pragma unroll
        for (int r = 0; r < 8; ++r) red[r][ks][cl] = A[r];
        __syncthreads();
        const float4 bias = *(const float4*)(bq + c);
        float4 s = bias;
        #pragma unroll
        for (int k = 0; k < 8; ++k) {
            const float4 p = red[orow][k][cl];
            s.x += p.x; s.y += p.y; s.z += p.z; s.w += p.w;
        }
        *(float4*)(q + (size_t)(r0 + orow) * H + c) = s;
    } else {
        float4 AK[8] = {}, AV[8] = {};
        const float4* Kp = (const float4*)(Wk + c);
        const float4* Vp = (const float4*)(Wv + c);
        float4 k0 = Kp[(e0 + 0) * H4], k1 = Kp[(e0 + 1) * H4];
        float4 u0 = Vp[(e0 + 0) * H4], u1 = Vp[(e0 + 1) * H4];
        int e = e0;
        #pragma unroll 1
        for (; e < e0 + 30; e += 2) {
            float4 nk0 = Kp[(e + 2) * H4], nk1 = Kp[(e + 3) * H4];
            float4 nu0 = Vp[(e + 2) * H4], nu1 = Vp[(e + 3) * H4];
            PROJ_STEP(e    , k0, AK);
            PROJ_STEP(e    , u0, AV);
            PROJ_STEP(e + 1, k1, AK);
            PROJ_STEP(e + 1, u1, AV);
            k0 = nk0; k1 = nk1; u0 = nu0; u1 = nu1;
        }
        PROJ_STEP(e    , k0, AK);
        PROJ_STEP(e    , u0, AV);
        PROJ_STEP(e + 1, k1, AK);
        PROJ_STEP(e + 1, u1, AV);

        // pass 1: reduce v-partials, store v (biased), keep per-thread copy
        #pragma unroll
        for (int r = 0; r < 8; ++r) red[r][ks][cl] = AV[r];
        __syncthreads();
        const float4 bv4 = *(const float4*)(bv + c);
        const float4 bk4 = *(const float4*)(bk + c);
        float4 vs = bv4;
        #pragma unroll
        for (int k = 0; k < 8; ++k) {
            const float4 p = red[orow][k][cl];
            vs.x += p.x; vs.y += p.y; vs.z += p.z; vs.w += p.w;
        }
        *(float4*)(v + (size_t)(r0 + orow) * H + c) = vs;
        __syncthreads();   // red reuse hazard

        // pass 2: reduce k-partials, kvT = ksum + bk + (vsum+bv)
        #pragma unroll
        for (int r = 0; r < 8; ++r) red[r][ks][cl] = AK[r];
        __syncthreads();
        float4 s;
        s.x = bk4.x + vs.x; s.y = bk4.y + vs.y;
        s.z = bk4.z + vs.z; s.w = bk4.w + vs.w;
        #pragma unroll
        for (int k = 0; k < 8; ++k) {
            const float4 p = red[orow][k][cl];
            s.x += p.x; s.y += p.y; s.z += p.z; s.w += p.w;
        }
        const int row = r0 + orow;
        const int bb = row >> 8, n = row & 255;
        kvT[((size_t)bb * H4 + (c >> 2)) * N + n] = s;
    }
}
#undef PROJ_STEP

// ---------------------------------------------------------------------------
// Energy via the identity  leaky_relu(s) = 0.505 s + 0.495 |s|:
//   energy[i,j] = row_const(i) + (0.505/0.495)*dot(kv_j, wb) + sum_h wb_h*|q+kv|
// with wb = 0.495*we. row_const is dropped (softmax shift-invariance).
// Unchanged from R2: at triple-point floor (VALU 2.75 ~ LDS 2.9 ~ kv-L2).
// ---------------------------------------------------------------------------
__global__ __launch_bounds__(512) void energy_kernel(
    const float* __restrict__ q, const float4* __restrict__ kvT,
    const float* __restrict__ wb, float* __restrict__ eout)
{
    __shared__ float qs[8][H];        // 24 KB
    __shared__ float wbs[H];          //  3 KB
    __shared__ float pE[8][16][64];   // [row][hq][j], 32 KB

    const int t    = threadIdx.x;
    const int jl   = t & 31;               // 0..31
    const int hq   = t >> 5;               // 0..15
    const int row0 = (blockIdx.x >> 2) * 8;
    const int j0   = (blockIdx.x & 3) * 64;
    const int b    = row0 >> 8;

    {
        float4* qs4 = (float4*)qs;
        const float4* qg = (const float4*)(q + (size_t)row0 * H);   // 8 contiguous rows
        #pragma unroll
        for (int i = 0; i < 3; ++i) qs4[t + 512 * i] = qg[t + 512 * i];
        if (t < H4) ((float4*)wbs)[t] = ((const float4*)wb)[t];
    }
    __syncthreads();

    const float4* kv0 = kvT + (size_t)b * H4 * N + (j0 + jl);   // stream 1 at +32
    const int base = hq * 12;                                   // 12 f4-idx per thread

    float acc0[8] = {0,0,0,0,0,0,0,0};
    float acc1[8] = {0,0,0,0,0,0,0,0};
    float4 ka0 = {0,0,0,0}, ka1 = {0,0,0,0};

#define ESTEP2(idx, u0_, u1_)                                                   \
    { const float4 wb4 = *(const float4*)&wbs[(idx) * 4];                       \
      ka0.x = fmaf(u0_.x, wb4.x, ka0.x); ka0.y = fmaf(u0_.y, wb4.y, ka0.y);     \
      ka0.z = fmaf(u0_.z, wb4.z, ka0.z); ka0.w = fmaf(u0_.w, wb4.w, ka0.w);     \
      ka1.x = fmaf(u1_.x, wb4.x, ka1.x); ka1.y = fmaf(u1_.y, wb4.y, ka1.y);     \
      ka1.z = fmaf(u1_.z, wb4.z, ka1.z); ka1.w = fmaf(u1_.w, wb4.w, ka1.w);     \
      _Pragma("unroll")                                                         \
      for (int r = 0; r < 8; ++r) {                                             \
          const float4 qa = *(const float4*)&qs[r][(idx) * 4];                  \
          float s;                                                              \
          s = qa.x + u0_.x; acc0[r] = fmaf(__builtin_fabsf(s), wb4.x, acc0[r]); \
          s = qa.x + u1_.x; acc1[r] = fmaf(__builtin_fabsf(s), wb4.x, acc1[r]); \
          s = qa.y + u0_.y; acc0[r] = fmaf(__builtin_fabsf(s), wb4.y, acc0[r]); \
          s = qa.y + u1_.y; acc1[r] = fmaf(__builtin_fabsf(s), wb4.y, acc1[r]); \
          s = qa.z + u0_.z; acc0[r] = fmaf(__builtin_fabsf(s), wb4.z, acc0[r]); \
          s = qa.z + u1_.z; acc1[r] = fmaf(__builtin_fabsf(s), wb4.z, acc1[r]); \
          s = qa.w + u0_.w; acc0[r] = fmaf(__builtin_fabsf(s), wb4.w, acc0[r]); \
          s = qa.w + u1_.w; acc1[r] = fmaf(__builtin_fabsf(s), wb4.w, acc1[r]); \
      } }

    float4 a0 = kv0[(base + 0) * N],      a1 = kv0[(base + 1) * N];
    float4 c0 = kv0[(base + 0) * N + 32], c1 = kv0[(base + 1) * N + 32];
    int it = 0;
    #pragma unroll 1
    for (; it < 10; it += 2) {
        float4 na0 = kv0[(base + it + 2) * N],      na1 = kv0[(base + it + 3) * N];
        float4 nc0 = kv0[(base + it + 2) * N + 32], nc1 = kv0[(base + it + 3) * N + 32];
        ESTEP2(base + it    , a0, c0);
        ESTEP2(base + it + 1, a1, c1);
        a0 = na0; a1 = na1; c0 = nc0; c1 = nc1;
    }
    ESTEP2(base + 10, a0, c0);
    ESTEP2(base + 11, a1, c1);
#undef ESTEP2

    const float KS = 0.505f / 0.495f;
    const float k0s = KS * ((ka0.x + ka0.y) + (ka0.z + ka0.w));
    const float k1s = KS * ((ka1.x + ka1.y) + (ka1.z + ka1.w));
    #pragma unroll
    for (int r = 0; r < 8; ++r) {
        pE[r][hq][jl]      = acc0[r] + k0s;
        pE[r][hq][jl + 32] = acc1[r] + k1s;
    }
    __syncthreads();

    const int rr = t >> 6, jc = t & 63;
    float ev = 0.f;
    #pragma unroll
    for (int k = 0; k < 16; ++k) ev += pE[rr][k][jc];
    eout[(size_t)(row0 + rr) * N + j0 + jc] = ev;
}

// ---------------------------------------------------------------------------
// Softmax + PV: 256 uniform blocks (exactly 1 per CU), 16 i-rows x 96 h,
// 384 threads (il = t/24 in 0..15, h4l = t%24). Kills the old 2-serial-block
// critical path; keeps 16-row v amortization (24 MB L2).
// Phase 1: 16 energy rows -> LDS; waves 0..3 softmax 4 rows each.
// Phase 2: out[i, 4h] = inv_s * sum_j p[j]*v[j,4h].
// ---------------------------------------------------------------------------
#define PSTEP(aj, vv, Am) \
    Am.x = fmaf(aj, vv.x, Am.x); Am.y = fmaf(aj, vv.y, Am.y); \
    Am.z = fmaf(aj, vv.z, Am.z); Am.w = fmaf(aj, vv.w, Am.w);

__global__ __launch_bounds__(384) void pv_kernel(
    const float* __restrict__ eout, const float* __restrict__ v,
    float* __restrict__ out)
{
    __shared__ float es[16][256];    // energies -> p values, 16 KB
    __shared__ float inv_s[16];

    const int t    = threadIdx.x;
    const int i0g  = (blockIdx.x >> 3) * 16;   // global row base (0..496)
    const int b    = i0g >> 8;
    const int ht   = blockIdx.x & 7;           // 96-col tile
    const int h4l  = t % 24;
    const int il   = t / 24;                   // 0..15

    {
        float4* es4 = (float4*)es;
        const float4* ep = (const float4*)(eout + (size_t)i0g * N);
        es4[t]       = ep[t];
        es4[t + 384] = ep[t + 384];
        if (t < 256) es4[t + 768] = ep[t + 768];
    }
    __syncthreads();

    // softmax: waves 0..3 own rows 4wv..4wv+3
    const int wv = t >> 6, ln = t & 63;
    if (wv < 4) {
        #pragma unroll
        for (int rr = 0; rr < 4; ++rr) {
            const int row = wv * 4 + rr;
            const float4 evv = ((const float4*)es[row])[ln];
            float m = fmaxf(fmaxf(evv.x, evv.y), fmaxf(evv.z, evv.w));
            #pragma unroll
            for (int off = 1; off < 64; off <<= 1) m = fmaxf(m, __shfl_xor(m, off));
            float4 p;
            p.x = __expf(evv.x - m); p.y = __expf(evv.y - m);
            p.z = __expf(evv.z - m); p.w = __expf(evv.w - m);
            float s = (p.x + p.y) + (p.z + p.w);
            #pragma unroll
            for (int off = 1; off < 64; off <<= 1) s += __shfl_xor(s, off);
            ((float4*)es[row])[ln] = p;
            if (ln == 0) inv_s[row] = 1.0f / s;
        }
    }
    __syncthreads();

    // PV: one f4 output column per thread
    const float4* vp = (const float4*)(v + (size_t)(b * 256) * H) + ht * 24 + h4l;
    const float4* a4 = (const float4*)es[il];

    float4 P = {0.f, 0.f, 0.f, 0.f}, Q = P;
    float4 av = a4[0];
    float4 v0 = vp[0], v1 = vp[H4], v2 = vp[2 * H4], v3 = vp[3 * H4];
    int j4 = 0;
    #pragma unroll 1
    for (; j4 < 63; ++j4) {
        const float4 nav = a4[j4 + 1];
        const int jb = 4 * j4 + 4;
        float4 n0 = vp[(jb + 0) * H4], n1 = vp[(jb + 1) * H4];
        float4 n2 = vp[(jb + 2) * H4], n3 = vp[(jb + 3) * H4];
        PSTEP(av.x, v0, P); PSTEP(av.y, v1, Q);
        PSTEP(av.z, v2, P); PSTEP(av.w, v3, Q);
        av = nav;
        v0 = n0; v1 = n1; v2 = n2; v3 = n3;
    }
    PSTEP(av.x, v0, P); PSTEP(av.y, v1, Q);
    PSTEP(av.z, v2, P); PSTEP(av.w, v3, Q);

    const float is = inv_s[il];
    float4 R;
    R.x = (P.x + Q.x) * is; R.y = (P.y + Q.y) * is;
    R.z = (P.z + Q.z) * is; R.w = (P.w + Q.w) * is;
    *(float4*)(out + (size_t)(i0g + il) * H + ht * 96 + h4l * 4) = R;
}

extern "C" void kernel_launch(void* const* d_in, const int* in_sizes, int n_in,
                              void* d_out, int out_size, void* d_ws, size_t ws_size,
                              hipStream_t stream) {
    const float* x  = (const float*)d_in[0];
    const float* Wq = (const float*)d_in[1];
    const float* bq = (const float*)d_in[2];
    const float* Wk = (const float*)d_in[3];
    const float* bk = (const float*)d_in[4];
    const float* Wv = (const float*)d_in[5];
    const float* bv = (const float*)d_in[6];
    const float* we = (const float*)d_in[7];
    float* out = (float*)d_out;

    float*  q    = (float*)d_ws;                 // [512][768]
    float*  v    = q + B * N * H;                // [512][768]
    float4* kvT  = (float4*)(v + B * N * H);     // [B][H4][N]
    float*  eout = (float*)(kvT + B * H4 * N);   // [512][256] shifted energies
    float*  wb   = eout + B * N * N;             // [768] = 0.495*we

    proj_kernel<<<768, 256, 0, stream>>>(x, Wq, bq, Wk, bk, Wv, bv, we, wb, q, v, kvT);
    energy_kernel<<<256, 512, 0, stream>>>(q, kvT, wb, eout);
    pv_kernel<<<256, 384, 0, stream>>>(eout, v, out);
}